// Round 2
// baseline (387.993 us; speedup 1.0000x reference)
//
#include <hip/hip_runtime.h>

// YOLOv1 loss, pred/labels (B,30,7,7) fp32 -> scalar.
// Memory-bound: ~385 MB read, ~61 us floor @6.3 TB/s achievable.
// R1 fix: coor2 uses labels ch5..8 (not ch0..3) per reference.

#define GRID 7
#define NCH 30
#define CPI (GRID * GRID)  // cells per image = 49

__device__ __forceinline__ float iou_xyxy(float x1a, float y1a, float x2a, float y2a,
                                          float x1b, float y1b, float x2b, float y2b) {
    float iw = fmaxf(fminf(x2a, x2b) - fmaxf(x1a, x1b), 0.0f);
    float ih = fmaxf(fminf(y2a, y2b) - fmaxf(y1a, y1b), 0.0f);
    float inter = iw * ih;
    float a1 = (x2a - x1a) * (y2a - y1a);
    float a2 = (x2b - x1b) * (y2b - y1b);
    float uni = a1 + a2 - inter;
    return inter > 0.0f ? inter / uni : 0.0f;
}

__global__ void __launch_bounds__(256) yolo_loss_kernel(
        const float* __restrict__ pred,
        const float* __restrict__ labels,
        float* __restrict__ out,
        int ncells, float invB) {
    int tid = blockIdx.x * blockDim.x + threadIdx.x;
    float acc = 0.0f;
    if (tid < ncells) {
        int b = tid / CPI;
        int cell = tid - b * CPI;
        int m = cell / GRID;          // dim-2 index, pairs with x
        int n = cell - m * GRID;      // dim-3 index, pairs with y

        const float* pb = pred   + (size_t)b * (NCH * CPI) + cell;
        const float* lb = labels + (size_t)b * (NCH * CPI) + cell;

        // pred channels 0..9
        float p0 = pb[0 * CPI], p1 = pb[1 * CPI], p2 = pb[2 * CPI], p3 = pb[3 * CPI];
        float p4 = pb[4 * CPI], p5 = pb[5 * CPI], p6 = pb[6 * CPI], p7 = pb[7 * CPI];
        float p8 = pb[8 * CPI], p9 = pb[9 * CPI];
        // labels channels 0..8 (ch9 unused)
        float l0 = lb[0 * CPI], l1 = lb[1 * CPI], l2 = lb[2 * CPI], l3 = lb[3 * CPI];
        float lobj = lb[4 * CPI];
        float l5 = lb[5 * CPI], l6 = lb[6 * CPI], l7 = lb[7 * CPI], l8 = lb[8 * CPI];

        // class term: channels 10..29
        float cls = 0.0f;
        #pragma unroll
        for (int c = 10; c < NCH; ++c) {
            float d = pb[c * CPI] - lb[c * CPI];
            cls += d * d;
        }

        const float inv_g = 1.0f / (float)GRID;
        float fm = (float)m, fn = (float)n;

        // box1 (pred 0..3)
        float cx = (p0 + fm) * inv_g, cy = (p1 + fn) * inv_g;
        float b1x1 = cx - p2 * 0.5f, b1y1 = cy - p3 * 0.5f;
        float b1x2 = cx + p2 * 0.5f, b1y2 = cy + p3 * 0.5f;
        // box2 (pred 5..8)
        cx = (p5 + fm) * inv_g; cy = (p6 + fn) * inv_g;
        float b2x1 = cx - p7 * 0.5f, b2y1 = cy - p8 * 0.5f;
        float b2x2 = cx + p7 * 0.5f, b2y2 = cy + p8 * 0.5f;
        // ground-truth box (labels 0..3)
        cx = (l0 + fm) * inv_g; cy = (l1 + fn) * inv_g;
        float gx1 = cx - l2 * 0.5f, gy1 = cy - l3 * 0.5f;
        float gx2 = cx + l2 * 0.5f, gy2 = cy + l3 * 0.5f;

        float iou1 = iou_xyxy(b1x1, b1y1, b1x2, b1y2, gx1, gy1, gx2, gy2);
        float iou2 = iou_xyxy(b2x1, b2y1, b2x2, b2y2, gx1, gy1, gx2, gy2);
        bool resp1 = iou1 >= iou2;

        // coor1: pred 0..3 vs labels 0..3
        float dx = p0 - l0, dy = p1 - l1;
        float dw = sqrtf(p2) - sqrtf(l2), dh = sqrtf(p3) - sqrtf(l3);
        float coor1 = 5.0f * (dx * dx + dy * dy + dw * dw + dh * dh);
        // coor2: pred 5..8 vs labels 5..8 (NOT the gt box!)
        dx = p5 - l5; dy = p6 - l6;
        dw = sqrtf(p7) - sqrtf(l7); dh = sqrtf(p8) - sqrtf(l8);
        float coor2 = 5.0f * (dx * dx + dy * dy + dw * dw + dh * dh);

        float e1 = p4 - iou1, e2 = p9 - iou2;
        float loss_b1 = coor1 + e1 * e1 + 0.5f * e2 * e2;
        float loss_b2 = coor2 + e2 * e2 + 0.5f * e1 * e1;

        float obj_loss = (resp1 ? loss_b1 : loss_b2) + cls;
        float noobj_loss = 0.5f * (p4 * p4 + p9 * p9);

        float contrib = (lobj == 1.0f) ? obj_loss : noobj_loss;
        acc = contrib * invB;
    }

    // wave (64-lane) shuffle reduction
    #pragma unroll
    for (int off = 32; off > 0; off >>= 1)
        acc += __shfl_down(acc, off, 64);

    __shared__ float smem[4];  // 256 threads = 4 waves
    int lane = threadIdx.x & 63;
    int wid = threadIdx.x >> 6;
    if (lane == 0) smem[wid] = acc;
    __syncthreads();
    if (threadIdx.x == 0) {
        float v = smem[0] + smem[1] + smem[2] + smem[3];
        atomicAdd(out, v);
    }
}

extern "C" void kernel_launch(void* const* d_in, const int* in_sizes, int n_in,
                              void* d_out, int out_size, void* d_ws, size_t ws_size,
                              hipStream_t stream) {
    const float* pred = (const float*)d_in[0];
    const float* labels = (const float*)d_in[1];
    float* out = (float*)d_out;

    int total = in_sizes[0];
    int B = total / (NCH * CPI);
    int ncells = B * CPI;

    hipMemsetAsync(out, 0, sizeof(float), stream);

    int block = 256;
    int grid = (ncells + block - 1) / block;
    yolo_loss_kernel<<<grid, block, 0, stream>>>(pred, labels, out, ncells, 1.0f / (float)B);
}